// Round 1
// 141.336 us; speedup vs baseline: 1.0148x; 1.0148x over previous
//
#include <hip/hip_runtime.h>
#include <hip/hip_fp16.h>

// InteractionBlock, MI355X, round 5.
//
// y = out @ W3 + gathersum(out) @ (W2@W3) + (b2@W3 + b3)
// R4 post-mortem: FETCH at its random-gather floor (153 MB) but only
// 3.3 TB/s and Occupancy 32% / VALUBusy 13% / MfmaUtil 1% -> latency-bound,
// not BW-bound. Limiter: 34.8 KB LDS (X tile + WT tile) caps at 4 blocks/CU.
// The WT tile is the same 16 KB for every block and fits in per-CU L1 ->
// staging it in LDS is pure occupancy loss. R5: drop WT LDS tile, read
// B-fragments straight from global WTg (L1-resident); LDS 17.4 KB ->
// launch_bounds(256,8) -> up to 8 blocks/CU (32 waves). Also merge wprep
// into pack (one fewer launch). Expect fused ~55 -> ~40 us at ~4.7 TB/s,
// FETCH unchanged.

constexpr int A  = 64;    // ao_vals
constexpr int K  = 32;    // neighbors
constexpr int GPB = 32;   // grid points per block (4 waves x 8)
constexpr int XS = 136;   // LDS row stride in halves (128 data + 8 pad)

typedef _Float16 f16x8 __attribute__((ext_vector_type(8)));
typedef float    f32x4 __attribute__((ext_vector_type(4)));

// ---- kernel 1 (merged prep):
//   blocks [0,16):   WTg[n][k] = (half) concat(W2@W3, W3)[k][n]  (n-major,
//                    128/row) and bb = b2@W3 + b3 (fp32)
//   blocks [16,...): pack out (fp32 [2][G][64]) -> packed ([G+1][64] half2)
//                    dword c of row g: c<32 -> batch0 pair (2c,2c+1); else b1.
//                    Row G is the materialized zero pad row (ws re-poisoned
//                    every launch, so it must be written every launch).
__global__ void prep_kernel(const float* __restrict__ W2, const float* __restrict__ b2,
                            const float* __restrict__ W3, const float* __restrict__ b3,
                            __half* __restrict__ WTg, float* __restrict__ bb,
                            const float2* __restrict__ out2,
                            __half2* __restrict__ packed, const int G) {
  if (blockIdx.x < 16) {
    const int e = blockIdx.x * 256 + threadIdx.x;   // 0..4095
    const int n = e >> 6, k = e & 63;
    float acc = 0.f;
#pragma unroll
    for (int q = 0; q < A; ++q) acc = fmaf(W2[k * A + q], W3[q * A + n], acc);
    WTg[n * 128 + k]     = __float2half(acc);           // W23 part (k rows 0..63)
    WTg[n * 128 + A + k] = __float2half(W3[k * A + n]); // W3 part (k rows 64..127)
    if (blockIdx.x == 0 && threadIdx.x < A) {
      const int t = threadIdx.x;
      float b = b3[t];
#pragma unroll
      for (int q = 0; q < A; ++q) b = fmaf(b2[q], W3[q * A + t], b);
      bb[t] = b;
    }
    return;
  }
  const int d = (blockIdx.x - 16) * 256 + threadIdx.x;
  const int total = (G + 1) * 64;
  if (d >= total) return;
  const int g = d >> 6, c = d & 63;
  float2 v = make_float2(0.f, 0.f);
  if (g < G) {
    const int b = c >> 5;
    v = out2[(size_t)b * (G * 32) + (size_t)g * 32 + (c & 31)];
  }
  packed[d] = __floats2half2_rn(v.x, v.y);
}

// ---- kernel 2: fused gather-sum + MFMA epilogue. 4 waves, 32 g per block ----
// LDS 17.4 KB (X only; WT read from global -> L1). 8 blocks/CU target.
__global__ __launch_bounds__(256, 8) void fused_kernel(
    const __half2* __restrict__ packed, const int* __restrict__ nbr,
    const __half* __restrict__ WTg, const float* __restrict__ bb,
    float* __restrict__ y, const int G) {
  __shared__ __half X[64 * XS];   // rows: b*32+gl ; cols: [m(64) | o(64)]

  const int tid = threadIdx.x;
  const int lane = tid & 63;
  const int w = __builtin_amdgcn_readfirstlane(tid >> 6);  // wave id, SGPR
  const int gbase = blockIdx.x * GPB;
  const int gcount = min(GPB, G - gbase);
  const int e = lane & 31;              // element-pair index
  const int rb = (lane >> 5) * 32;      // row base: batch = lane>>5

  const __half2 z = __floats2half2_rn(0.f, 0.f);

  // Phase 1: each wave gather-sums 8 grid points (fp16 accumulate, 4 chains).
#pragma unroll
  for (int gg = 0; gg < 8; ++gg) {
    const int gl = w * 8 + gg;          // wave-uniform
    if (gl < gcount) {
      const int g = gbase + gl;
      const int* np = nbr + g * K;      // uniform pointer -> s_load indices
      __half2 m0 = z, m1 = z, m2 = z, m3 = z;
#pragma unroll
      for (int k = 0; k < K; k += 4) {
        const __half2 u0 = packed[(size_t)np[k]     * 64 + lane];
        const __half2 u1 = packed[(size_t)np[k + 1] * 64 + lane];
        const __half2 u2 = packed[(size_t)np[k + 2] * 64 + lane];
        const __half2 u3 = packed[(size_t)np[k + 3] * 64 + lane];
        m0 = __hadd2(m0, u0);
        m1 = __hadd2(m1, u1);
        m2 = __hadd2(m2, u2);
        m3 = __hadd2(m3, u3);
      }
      const __half2 m = __hadd2(__hadd2(m0, m1), __hadd2(m2, m3));
      const __half2 o = packed[(size_t)g * 64 + lane];   // residual row
      const int r = rb + gl;
      *(__half2*)&X[r * XS + 2 * e]     = m;
      *(__half2*)&X[r * XS + A + 2 * e] = o;
    }
  }
  __syncthreads();

  // Phase 2: Y[64x64] = X[64x128] @ WcatT^T, wave w does rows w*16..w*16+15.
  // A-frag: A[m=lane&15][k=quad*8+j]; B-frag: B[k=quad*8+j][n=lane&15];
  // C/D: col=lane&15, row=quad*4+reg (HW-verified, dtype-independent).
  // B-frags come straight from global WTg (16 KB, identical for all blocks
  // -> L1-resident; MfmaUtil was 1%, this phase is not the bottleneck).
  const int quad = lane >> 4;
  const int mn = lane & 15;
  f32x4 acc0 = {0.f, 0.f, 0.f, 0.f};
  f32x4 acc1 = {0.f, 0.f, 0.f, 0.f};
  f32x4 acc2 = {0.f, 0.f, 0.f, 0.f};
  f32x4 acc3 = {0.f, 0.f, 0.f, 0.f};
#pragma unroll
  for (int kt = 0; kt < 4; ++kt) {
    const int ko = kt * 32 + quad * 8;
    const f16x8 a = *(const f16x8*)&X[(w * 16 + mn) * XS + ko];
    const f16x8 b0 = *(const f16x8*)&WTg[(0 * 16 + mn) * 128 + ko];
    acc0 = __builtin_amdgcn_mfma_f32_16x16x32_f16(a, b0, acc0, 0, 0, 0);
    const f16x8 b1 = *(const f16x8*)&WTg[(1 * 16 + mn) * 128 + ko];
    acc1 = __builtin_amdgcn_mfma_f32_16x16x32_f16(a, b1, acc1, 0, 0, 0);
    const f16x8 b2 = *(const f16x8*)&WTg[(2 * 16 + mn) * 128 + ko];
    acc2 = __builtin_amdgcn_mfma_f32_16x16x32_f16(a, b2, acc2, 0, 0, 0);
    const f16x8 b3 = *(const f16x8*)&WTg[(3 * 16 + mn) * 128 + ko];
    acc3 = __builtin_amdgcn_mfma_f32_16x16x32_f16(a, b3, acc3, 0, 0, 0);
  }

  // Store + bias. Row r = w*16 + quad*4 + reg -> (batch r>>5, gl = r&31).
  f32x4 accs[4] = {acc0, acc1, acc2, acc3};
#pragma unroll
  for (int nt = 0; nt < 4; ++nt) {
    const int col = nt * 16 + mn;
    const float bv = bb[col];
#pragma unroll
    for (int rg = 0; rg < 4; ++rg) {
      const int row = w * 16 + quad * 4 + rg;
      const int b = row >> 5, gl = row & 31;
      if (gl < gcount)
        y[((size_t)b * G + (gbase + gl)) * 64 + col] = accs[nt][rg] + bv;
    }
  }
}

extern "C" void kernel_launch(void* const* d_in, const int* in_sizes, int n_in,
                              void* d_out, int out_size, void* d_ws, size_t ws_size,
                              hipStream_t stream) {
  const float* out = (const float*)d_in[0];
  const int*   nbr = (const int*)d_in[1];
  const float* W2  = (const float*)d_in[2];
  const float* b2  = (const float*)d_in[3];
  const float* W3  = (const float*)d_in[4];
  const float* b3  = (const float*)d_in[5];
  float* y = (float*)d_out;
  const int G = in_sizes[1] / K;

  // ws: packed rows | WTg (fp16 128x64 transposed concat) | bb (fp32 64)
  __half2* packed = (__half2*)d_ws;                       // (G+1)*64 half2
  const size_t packedBytes = (size_t)(G + 1) * 64 * sizeof(__half2);
  __half* WTg = (__half*)((char*)d_ws + packedBytes);     // 8192 halves
  float* bb = (float*)((char*)d_ws + packedBytes + 8192 * sizeof(__half));

  const int packTotal = (G + 1) * 64;
  const int prepBlocks = 16 + (packTotal + 255) / 256;
  prep_kernel<<<prepBlocks, 256, 0, stream>>>(W2, b2, W3, b3, WTg, bb,
                                              (const float2*)out, packed, G);

  const int blocks = (G + GPB - 1) / GPB;
  fused_kernel<<<blocks, 256, 0, stream>>>(packed, nbr, WTg, bb, y, G);
}